// Round 2
// baseline (191.751 us; speedup 1.0000x reference)
//
#include <hip/hip_runtime.h>
#include <math.h>

#define DIMX 128
#define HIDX 256
#define NBX 2048
#define NTOTX 32768
#define NMAXX 32
#define VMID 192
#define SMID 128
#define DMID 192
#define KTAB 256

#define EROWS 64
#define PITCH 66   // odd*2: staging/act writes spread banks, float2-aligned reads

__device__ __forceinline__ float mishf(float v) {
    // exact identity: tanh(log1p(e^v)) = (u^2+2u)/(u^2+2u+2), u=e^v
    if (v > 20.0f) return v;          // tanh(softplus(v)) == 1.0f in fp32
    float u = expf(v);
    float t = u * (u + 2.0f);
    return v * (t / (t + 2.0f));
}

// fused prep: mag dot, key table, segment bounds, wcount reset, output zero
__global__ void k_prep(const float* __restrict__ x, const float* __restrict__ rw,
                       const float* __restrict__ rb, const int* __restrict__ batch,
                       float* __restrict__ mag, int* __restrict__ segs,
                       int* __restrict__ segn, float* __restrict__ ct,
                       float* __restrict__ st, int* __restrict__ wcount,
                       float4* __restrict__ xrz) {
    int blk = blockIdx.x, tid = threadIdx.x;
    if (blk < 8192) {                       // mag: 4 rows/block, 1 wave/row
        int gid = blk * 256 + tid;
        int row = gid >> 6, lane = gid & 63;
        const float* xr = x + (size_t)row * DIMX;
        float s = xr[lane] * rw[lane] + xr[lane + 64] * rw[lane + 64];
#pragma unroll
        for (int off = 32; off; off >>= 1) s += __shfl_down(s, off, 64);
        if (lane == 0) mag[row] = s + rb[0];
    } else if (blk < 8448) {                // key table, k = blk-8192
        int k = blk - 8192;
        float t = (float)tid * (1.0f / 255.0f);
        float th = (t * (float)k) * 8.0f;
        float sv, cv;
        sincosf(th, &sv, &cv);
        ct[k * HIDX + tid] = cv;
        st[k * HIDX + tid] = sv;
    } else if (blk == 8448) {               // segment bounds + wcount reset
        if (tid == 0) wcount[0] = 0;
        for (int b = tid; b < NBX; b += 256) {
            int lo = 0, hi = NTOTX;
            while (lo < hi) { int m = (lo + hi) >> 1; if (batch[m] < b) lo = m + 1; else hi = m; }
            int stt = lo;
            hi = NTOTX;
            while (lo < hi) { int m = (lo + hi) >> 1; if (batch[m] <= b) lo = m + 1; else hi = m; }
            segs[b] = stt; segn[b] = lo - stt;
        }
    } else {                                // zero out_xr: 2048 blocks x 1024 f4
        int base = (blk - 8449) * 1024 + tid;
#pragma unroll
        for (int q = 0; q < 4; q++)
            xrz[base + q * 256] = make_float4(0.f, 0.f, 0.f, 0.f);
    }
}

// stable rank within segment -> order[]
__global__ void k_rank(const int* __restrict__ batch, const float* __restrict__ mag,
                       const int* __restrict__ segs, const int* __restrict__ segn,
                       int* __restrict__ order) {
    int i = blockIdx.x * blockDim.x + threadIdx.x;
    if (i >= NTOTX) return;
    int b = batch[i];
    int s = segs[b], e = s + segn[b];
    float mi = mag[i];
    int r = 0;
    for (int j = s; j < e; j++) {
        float mj = mag[j];
        r += (mj < mi) || (mj == mi && j < i);
    }
    order[s + r] = i;
}

// fused encoder: h = mish(LN(x@w1+b1))@w2 + b2 ; 64 rows/block, 256 thr
__global__ __launch_bounds__(256) void k_enc(const float* __restrict__ x,
    const float* __restrict__ w1, const float* __restrict__ b1,
    const float* __restrict__ g1, const float* __restrict__ be1,
    const float* __restrict__ w2, const float* __restrict__ b2,
    float* __restrict__ h) {
    __shared__ __align__(16) float sT[VMID * PITCH];  // reused: x^T then act^T
    int tid = threadIdx.x;
    int rowbase = blockIdx.x * EROWS;

    // stage x^T: coalesced float4 reads, scattered b32 writes (one-time)
#pragma unroll
    for (int it = 0; it < 8; it++) {
        int idx = it * 256 + tid;
        int r = idx >> 5, kq = idx & 31;
        float4 v = ((const float4*)x)[(size_t)(rowbase + r) * 32 + kq];
        sT[(4 * kq + 0) * PITCH + r] = v.x;
        sT[(4 * kq + 1) * PITCH + r] = v.y;
        sT[(4 * kq + 2) * PITCH + r] = v.z;
        sT[(4 * kq + 3) * PITCH + r] = v.w;
    }
    __syncthreads();

    int c = tid & 63;      // col base (lane)
    int rg = tid >> 6;     // row group of 16
    int r0 = rg * 16;

    // ---- GEMM1: 48 FMA per 3 weight loads ----
    float a0[16], a1[16], a2[16];
#pragma unroll
    for (int i = 0; i < 16; i++) { a0[i] = 0.f; a1[i] = 0.f; a2[i] = 0.f; }
    const float* w1p = w1 + c;
#pragma unroll 2
    for (int k = 0; k < DIMX; k++) {
        float wa = w1p[k * VMID];
        float wb = w1p[k * VMID + 64];
        float wc = w1p[k * VMID + 128];
        const float2* xp = (const float2*)&sT[k * PITCH + r0];
        float xv[16];
#pragma unroll
        for (int q = 0; q < 8; q++) { float2 t2 = xp[q]; xv[2 * q] = t2.x; xv[2 * q + 1] = t2.y; }
#pragma unroll
        for (int i = 0; i < 16; i++) {
            a0[i] += wa * xv[i];
            a1[i] += wb * xv[i];
            a2[i] += wc * xv[i];
        }
    }

    // ---- LayerNorm + mish (in regs) ----
    float b1a = b1[c], b1b = b1[c + 64], b1c = b1[c + 128];
    float g1a = g1[c], g1b = g1[c + 64], g1c = g1[c + 128];
    float e1a = be1[c], e1b = be1[c + 64], e1c = be1[c + 128];
#pragma unroll
    for (int i = 0; i < 16; i++) {
        float v0 = a0[i] + b1a, v1 = a1[i] + b1b, v2 = a2[i] + b1c;
        float s = v0 + v1 + v2;
#pragma unroll
        for (int off = 32; off; off >>= 1) s += __shfl_xor(s, off, 64);
        float mean = s / 192.0f;
        float d0 = v0 - mean, d1 = v1 - mean, d2 = v2 - mean;
        float q = d0 * d0 + d1 * d1 + d2 * d2;
#pragma unroll
        for (int off = 32; off; off >>= 1) q += __shfl_xor(q, off, 64);
        float inv = 1.0f / sqrtf(q / 192.0f + 1e-5f);
        a0[i] = mishf(d0 * inv * g1a + e1a);
        a1[i] = mishf(d1 * inv * g1b + e1b);
        a2[i] = mishf(d2 * inv * g1c + e1c);
    }
    __syncthreads();   // all GEMM1 LDS reads done before overwrite
#pragma unroll
    for (int i = 0; i < 16; i++) {
        sT[c * PITCH + r0 + i]          = a0[i];
        sT[(c + 64) * PITCH + r0 + i]   = a1[i];
        sT[(c + 128) * PITCH + r0 + i]  = a2[i];
    }
    __syncthreads();

    // ---- GEMM2: 64 FMA per 4 weight loads (reuse a0..a2 as accum) ----
    float a3[16];
#pragma unroll
    for (int i = 0; i < 16; i++) { a0[i] = 0.f; a1[i] = 0.f; a2[i] = 0.f; a3[i] = 0.f; }
    const float* w2p = w2 + c;
#pragma unroll 2
    for (int k = 0; k < VMID; k++) {
        float wa = w2p[k * HIDX];
        float wb = w2p[k * HIDX + 64];
        float wc = w2p[k * HIDX + 128];
        float wd = w2p[k * HIDX + 192];
        const float2* ap = (const float2*)&sT[k * PITCH + r0];
        float av[16];
#pragma unroll
        for (int q = 0; q < 8; q++) { float2 t2 = ap[q]; av[2 * q] = t2.x; av[2 * q + 1] = t2.y; }
#pragma unroll
        for (int i = 0; i < 16; i++) {
            a0[i] += wa * av[i];
            a1[i] += wb * av[i];
            a2[i] += wc * av[i];
            a3[i] += wd * av[i];
        }
    }
    float b2a = b2[c], b2b = b2[c + 64], b2c = b2[c + 128], b2d = b2[c + 192];
#pragma unroll
    for (int i = 0; i < 16; i++) {
        size_t row = (size_t)(rowbase + r0 + i);
        h[row * HIDX + c]        = a0[i] + b2a;
        h[row * HIDX + c + 64]   = a1[i] + b2b;
        h[row * HIDX + c + 128]  = a2[i] + b2c;
        h[row * HIDX + c + 192]  = a3[i] + b2d;
    }
}

// fused: z (segment sum of h*keys + card) -> size MLP -> n_pred, mask, zc, worklist
__global__ __launch_bounds__(256) void k_z(const float* __restrict__ h,
    const int* __restrict__ order, const int* __restrict__ segs, const int* __restrict__ segn,
    const float* __restrict__ ct, const float* __restrict__ st,
    const float* __restrict__ cw, const float* __restrict__ cb,
    const float* __restrict__ sw1, const float* __restrict__ sb1,
    const float* __restrict__ sg, const float* __restrict__ sbe,
    const float* __restrict__ sw2, const float* __restrict__ sb2,
    float* __restrict__ zcre, float* __restrict__ zim,
    float* __restrict__ out_mask, float* __restrict__ out_np,
    int* __restrict__ wcount, int* __restrict__ wlist) {
    __shared__ float zrow[HIDX];
    __shared__ float red0[2], red1[2], red2[2];
    int b = blockIdx.x, j = threadIdx.x;
    int s = segs[b], n = segn[b];
    float zr = 0.f, zi = 0.f;
    for (int p = 0; p < n; p++) {
        int e = order[s + p];
        float hv = h[(size_t)e * HIDX + j];
        float cv, sv;
        if (p < KTAB) { cv = ct[p * HIDX + j]; sv = st[p * HIDX + j]; }
        else {
            float t = (float)j * (1.0f / 255.0f);
            float th = (t * (float)p) * 8.0f;
            sincosf(th, &sv, &cv);
        }
        zr += hv * cv; zi += hv * sv;
    }
    float nf = (float)n;
    float zrev = zr + nf * cw[j] + cb[j];
    zrow[j] = zrev;
    zim[(size_t)b * HIDX + j] = zi;
    __syncthreads();

    // size MLP (threads 0..127 active; all threads hit barriers)
    float v = 0.0f;
    if (j < SMID) {
        v = sb1[j];
        for (int k = 0; k < HIDX; k++) v += zrow[k] * sw1[k * SMID + j];
    }
    float sa = v;
#pragma unroll
    for (int off = 32; off; off >>= 1) sa += __shfl_xor(sa, off, 64);
    if (j < SMID && (j & 63) == 0) red0[j >> 6] = sa;
    __syncthreads();
    float mean = (red0[0] + red0[1]) / 128.0f;
    float d = v - mean;
    float q = d * d;
#pragma unroll
    for (int off = 32; off; off >>= 1) q += __shfl_xor(q, off, 64);
    if (j < SMID && (j & 63) == 0) red1[j >> 6] = q;
    __syncthreads();
    float var = (red1[0] + red1[1]) / 128.0f;
    float p2 = 0.0f;
    if (j < SMID) {
        float lv = d * (1.0f / sqrtf(var + 1e-5f)) * sg[j] + sbe[j];
        p2 = mishf(lv) * sw2[j];
    }
#pragma unroll
    for (int off = 32; off; off >>= 1) p2 += __shfl_xor(p2, off, 64);
    if (j < SMID && (j & 63) == 0) red2[j >> 6] = p2;
    __syncthreads();
    float h2 = red2[0] + red2[1] + sb2[0];
    float npf = fmaxf(rintf(h2), 0.0f);     // rintf == round-half-even == jnp.round
    int npi = min((int)npf, NMAXX);
    zcre[(size_t)b * HIDX + j] = zrow[j] - (npf * cw[j] + cb[j]);
    if (j < NMAXX) out_mask[b * NMAXX + j] = (j < npi) ? 1.0f : 0.0f;
    if (j == 0) {
        out_np[b] = (float)npi;
        int base = atomicAdd(wcount, npi);
        for (int m = 0; m < npi; m++) wlist[base + m] = (b << 5) | m;
    }
}

// decoder over compacted worklist
__global__ __launch_bounds__(256) void k_dec(const float* __restrict__ zcre,
    const float* __restrict__ zim, const int* __restrict__ wcount,
    const int* __restrict__ wlist, const float* __restrict__ ct,
    const float* __restrict__ st, const float* __restrict__ w1,
    const float* __restrict__ b1, const float* __restrict__ w2,
    const float* __restrict__ b2, float* __restrict__ xr) {
    __shared__ float zp[HIDX];
    __shared__ float a[DMID];
    int tid = threadIdx.x;
    int count = *wcount;
    for (int it = blockIdx.x; it < count; it += gridDim.x) {
        int wv = wlist[it];
        int b = wv >> 5, m = wv & 31;
        float cv = ct[m * HIDX + tid], sv = st[m * HIDX + tid];
        zp[tid] = zcre[(size_t)b * HIDX + tid] * cv - zim[(size_t)b * HIDX + tid] * sv;
        __syncthreads();
        if (tid < DMID) {
            float v = b1[tid];
            for (int k = 0; k < HIDX; k++) v += zp[k] * w1[k * DMID + tid];
            a[tid] = mishf(v);
        }
        __syncthreads();
        if (tid < DIMX) {
            float v = b2[tid];
            for (int k = 0; k < DMID; k++) v += a[k] * w2[k * DIMX + tid];
            xr[((size_t)b * NMAXX + m) * DIMX + tid] = v;
        }
        __syncthreads();
    }
}

extern "C" void kernel_launch(void* const* d_in, const int* in_sizes, int n_in,
                              void* d_out, int out_size, void* d_ws, size_t ws_size,
                              hipStream_t stream) {
    const float* x      = (const float*)d_in[0];
    const int*   batch  = (const int*)d_in[1];
    const float* rank_w = (const float*)d_in[2];
    const float* rank_b = (const float*)d_in[3];
    const float* vw1    = (const float*)d_in[4];
    const float* vb1    = (const float*)d_in[5];
    const float* vlg    = (const float*)d_in[6];
    const float* vlb    = (const float*)d_in[7];
    const float* vw2    = (const float*)d_in[8];
    const float* vb2    = (const float*)d_in[9];
    const float* cw     = (const float*)d_in[10];
    const float* cb     = (const float*)d_in[11];
    const float* sw1    = (const float*)d_in[12];
    const float* sb1    = (const float*)d_in[13];
    const float* slg    = (const float*)d_in[14];
    const float* slb    = (const float*)d_in[15];
    const float* sw2    = (const float*)d_in[16];
    const float* sb2    = (const float*)d_in[17];
    const float* dw1    = (const float*)d_in[18];
    const float* db1    = (const float*)d_in[19];
    const float* dw2    = (const float*)d_in[20];
    const float* db2    = (const float*)d_in[21];

    char* ws = (char*)d_ws;
    size_t off = 0;
    auto alloc = [&](size_t bytes) {
        void* p = ws + off;
        off += (bytes + 255) & ~(size_t)255;
        return p;
    };
    float* mag    = (float*)alloc((size_t)NTOTX * 4);
    int*   segs   = (int*)alloc((size_t)NBX * 4);
    int*   segn   = (int*)alloc((size_t)NBX * 4);
    int*   order  = (int*)alloc((size_t)NTOTX * 4);
    float* ct     = (float*)alloc((size_t)KTAB * HIDX * 4);
    float* st     = (float*)alloc((size_t)KTAB * HIDX * 4);
    float* zim    = (float*)alloc((size_t)NBX * HIDX * 4);
    float* zcre   = (float*)alloc((size_t)NBX * HIDX * 4);
    int*   wcount = (int*)alloc(256);
    int*   wlist  = (int*)alloc((size_t)NBX * NMAXX * 4);
    float* h      = (float*)alloc((size_t)NTOTX * HIDX * 4);

    float* out_xr   = (float*)d_out;
    float* out_mask = out_xr + (size_t)NBX * NMAXX * DIMX;
    float* out_np   = out_mask + (size_t)NBX * NMAXX;

    hipLaunchKernelGGL(k_prep, dim3(8449 + 2048), dim3(256), 0, stream,
                       x, rank_w, rank_b, batch, mag, segs, segn, ct, st,
                       wcount, (float4*)out_xr);
    hipLaunchKernelGGL(k_rank, dim3(NTOTX / 256), dim3(256), 0, stream,
                       batch, mag, segs, segn, order);
    hipLaunchKernelGGL(k_enc,  dim3(NTOTX / EROWS), dim3(256), 0, stream,
                       x, vw1, vb1, vlg, vlb, vw2, vb2, h);
    hipLaunchKernelGGL(k_z,    dim3(NBX), dim3(HIDX), 0, stream,
                       h, order, segs, segn, ct, st, cw, cb,
                       sw1, sb1, slg, slb, sw2, sb2,
                       zcre, zim, out_mask, out_np, wcount, wlist);
    hipLaunchKernelGGL(k_dec,  dim3(2048), dim3(256), 0, stream,
                       zcre, zim, wcount, wlist, ct, st, dw1, db1, dw2, db2, out_xr);
    (void)in_sizes; (void)n_in; (void)out_size; (void)ws_size;
}

// Round 3
// 185.082 us; speedup vs baseline: 1.0360x; 1.0360x over previous
//
#include <hip/hip_runtime.h>
#include <math.h>

#define DIMX 128
#define HIDX 256
#define NBX 2048
#define NTOTX 32768
#define NMAXX 32
#define VMID 192
#define SMID 128
#define DMID 192
#define KTAB 256

#define EROWS 32
#define PITCH 34   // 34*4B stride: float2-aligned, bank stride 2 -> broadcast reads OK

__device__ __forceinline__ float mishf(float v) {
    // exact identity: tanh(log1p(e^v)) = (u^2+2u)/(u^2+2u+2), u=e^v
    if (v > 20.0f) return v;          // tanh(softplus(v)) == 1.0f in fp32
    float u = expf(v);
    float t = u * (u + 2.0f);
    return v * (t / (t + 2.0f));
}

// fused prep: mag dot, key table, segment bounds, wcount reset, output zero
__global__ void k_prep(const float* __restrict__ x, const float* __restrict__ rw,
                       const float* __restrict__ rb, const int* __restrict__ batch,
                       float* __restrict__ mag, int* __restrict__ segs,
                       int* __restrict__ segn, float* __restrict__ ct,
                       float* __restrict__ st, int* __restrict__ wcount,
                       float4* __restrict__ xrz) {
    int blk = blockIdx.x, tid = threadIdx.x;
    if (blk < 8192) {                       // mag: 4 rows/block, 1 wave/row
        int gid = blk * 256 + tid;
        int row = gid >> 6, lane = gid & 63;
        const float* xr = x + (size_t)row * DIMX;
        float s = xr[lane] * rw[lane] + xr[lane + 64] * rw[lane + 64];
#pragma unroll
        for (int off = 32; off; off >>= 1) s += __shfl_down(s, off, 64);
        if (lane == 0) mag[row] = s + rb[0];
    } else if (blk < 8448) {                // key table, k = blk-8192
        int k = blk - 8192;
        float t = (float)tid * (1.0f / 255.0f);
        float th = (t * (float)k) * 8.0f;
        float sv, cv;
        sincosf(th, &sv, &cv);
        ct[k * HIDX + tid] = cv;
        st[k * HIDX + tid] = sv;
    } else if (blk == 8448) {               // segment bounds + wcount reset
        if (tid == 0) wcount[0] = 0;
        for (int b = tid; b < NBX; b += 256) {
            int lo = 0, hi = NTOTX;
            while (lo < hi) { int m = (lo + hi) >> 1; if (batch[m] < b) lo = m + 1; else hi = m; }
            int stt = lo;
            hi = NTOTX;
            while (lo < hi) { int m = (lo + hi) >> 1; if (batch[m] <= b) lo = m + 1; else hi = m; }
            segs[b] = stt; segn[b] = lo - stt;
        }
    } else {                                // zero out_xr: 2048 blocks x 1024 f4
        int base = (blk - 8449) * 1024 + tid;
#pragma unroll
        for (int q = 0; q < 4; q++)
            xrz[base + q * 256] = make_float4(0.f, 0.f, 0.f, 0.f);
    }
}

// stable rank within segment -> order[]
__global__ void k_rank(const int* __restrict__ batch, const float* __restrict__ mag,
                       const int* __restrict__ segs, const int* __restrict__ segn,
                       int* __restrict__ order) {
    int i = blockIdx.x * blockDim.x + threadIdx.x;
    if (i >= NTOTX) return;
    int b = batch[i];
    int s = segs[b], e = s + segn[b];
    float mi = mag[i];
    int r = 0;
    for (int j = s; j < e; j++) {
        float mj = mag[j];
        r += (mj < mi) || (mj == mi && j < i);
    }
    order[s + r] = i;
}

// fused encoder: h = mish(LN(x@w1+b1))@w2 + b2 ; 32 rows/block, 256 thr,
// single 26.1KB LDS buffer -> 6 blocks/CU (75% occupancy)
__global__ __launch_bounds__(256, 6) void k_enc(const float* __restrict__ x,
    const float* __restrict__ w1, const float* __restrict__ b1,
    const float* __restrict__ g1, const float* __restrict__ be1,
    const float* __restrict__ w2, const float* __restrict__ b2,
    float* __restrict__ h) {
    __shared__ __align__(16) float sT[VMID * PITCH];  // reused: x^T then act^T
    int tid = threadIdx.x;
    int rowbase = blockIdx.x * EROWS;

    // stage x^T: coalesced float4 reads, scattered b32 writes (one-time)
#pragma unroll
    for (int it = 0; it < 4; it++) {
        int idx = it * 256 + tid;
        int r = idx >> 5, kq = idx & 31;
        float4 v = ((const float4*)x)[(size_t)(rowbase + r) * 32 + kq];
        sT[(4 * kq + 0) * PITCH + r] = v.x;
        sT[(4 * kq + 1) * PITCH + r] = v.y;
        sT[(4 * kq + 2) * PITCH + r] = v.z;
        sT[(4 * kq + 3) * PITCH + r] = v.w;
    }
    __syncthreads();

    int c = tid & 63;      // col base (lane)
    int rg = tid >> 6;     // row group of 8
    int r0 = rg * 8;

    // ---- GEMM1: 24 FMA per 3 weight loads ----
    float a0[8], a1[8], a2[8];
#pragma unroll
    for (int i = 0; i < 8; i++) { a0[i] = 0.f; a1[i] = 0.f; a2[i] = 0.f; }
    const float* w1p = w1 + c;
#pragma unroll 2
    for (int k = 0; k < DIMX; k++) {
        float wa = w1p[k * VMID];
        float wb = w1p[k * VMID + 64];
        float wc = w1p[k * VMID + 128];
        const float2* xp = (const float2*)&sT[k * PITCH + r0];
        float xv[8];
#pragma unroll
        for (int q = 0; q < 4; q++) { float2 t2 = xp[q]; xv[2 * q] = t2.x; xv[2 * q + 1] = t2.y; }
#pragma unroll
        for (int i = 0; i < 8; i++) {
            a0[i] += wa * xv[i];
            a1[i] += wb * xv[i];
            a2[i] += wc * xv[i];
        }
    }

    // ---- LayerNorm + mish (registers + shuffles only) ----
    float b1a = b1[c], b1b = b1[c + 64], b1c = b1[c + 128];
    float g1a = g1[c], g1b = g1[c + 64], g1c = g1[c + 128];
    float e1a = be1[c], e1b = be1[c + 64], e1c = be1[c + 128];
#pragma unroll
    for (int i = 0; i < 8; i++) {
        float v0 = a0[i] + b1a, v1 = a1[i] + b1b, v2 = a2[i] + b1c;
        float s = v0 + v1 + v2;
#pragma unroll
        for (int off = 32; off; off >>= 1) s += __shfl_xor(s, off, 64);
        float mean = s / 192.0f;
        float d0 = v0 - mean, d1 = v1 - mean, d2 = v2 - mean;
        float q = d0 * d0 + d1 * d1 + d2 * d2;
#pragma unroll
        for (int off = 32; off; off >>= 1) q += __shfl_xor(q, off, 64);
        float inv = 1.0f / sqrtf(q / 192.0f + 1e-5f);
        a0[i] = mishf(d0 * inv * g1a + e1a);
        a1[i] = mishf(d1 * inv * g1b + e1b);
        a2[i] = mishf(d2 * inv * g1c + e1c);
    }
    __syncthreads();   // all GEMM1 LDS reads done before overwrite
#pragma unroll
    for (int i = 0; i < 8; i++) {
        sT[c * PITCH + r0 + i]          = a0[i];
        sT[(c + 64) * PITCH + r0 + i]   = a1[i];
        sT[(c + 128) * PITCH + r0 + i]  = a2[i];
    }
    __syncthreads();

    // ---- GEMM2: 32 FMA per 4 weight loads ----
    float c0[8], c1[8], c2[8], c3[8];
#pragma unroll
    for (int i = 0; i < 8; i++) { c0[i] = 0.f; c1[i] = 0.f; c2[i] = 0.f; c3[i] = 0.f; }
    const float* w2p = w2 + c;
#pragma unroll 2
    for (int k = 0; k < VMID; k++) {
        float wa = w2p[k * HIDX];
        float wb = w2p[k * HIDX + 64];
        float wc = w2p[k * HIDX + 128];
        float wd = w2p[k * HIDX + 192];
        const float2* ap = (const float2*)&sT[k * PITCH + r0];
        float av[8];
#pragma unroll
        for (int q = 0; q < 4; q++) { float2 t2 = ap[q]; av[2 * q] = t2.x; av[2 * q + 1] = t2.y; }
#pragma unroll
        for (int i = 0; i < 8; i++) {
            c0[i] += wa * av[i];
            c1[i] += wb * av[i];
            c2[i] += wc * av[i];
            c3[i] += wd * av[i];
        }
    }
    float b2a = b2[c], b2b = b2[c + 64], b2c = b2[c + 128], b2d = b2[c + 192];
#pragma unroll
    for (int i = 0; i < 8; i++) {
        size_t row = (size_t)(rowbase + r0 + i);
        h[row * HIDX + c]        = c0[i] + b2a;
        h[row * HIDX + c + 64]   = c1[i] + b2b;
        h[row * HIDX + c + 128]  = c2[i] + b2c;
        h[row * HIDX + c + 192]  = c3[i] + b2d;
    }
}

// fused: z (segment sum of h*keys + card) -> size MLP -> n_pred, mask, zc, worklist
__global__ __launch_bounds__(256) void k_z(const float* __restrict__ h,
    const int* __restrict__ order, const int* __restrict__ segs, const int* __restrict__ segn,
    const float* __restrict__ ct, const float* __restrict__ st,
    const float* __restrict__ cw, const float* __restrict__ cb,
    const float* __restrict__ sw1, const float* __restrict__ sb1,
    const float* __restrict__ sg, const float* __restrict__ sbe,
    const float* __restrict__ sw2, const float* __restrict__ sb2,
    float* __restrict__ zcre, float* __restrict__ zim,
    float* __restrict__ out_mask, float* __restrict__ out_np,
    int* __restrict__ wcount, int* __restrict__ wlist) {
    __shared__ float zrow[HIDX];
    __shared__ float red0[2], red1[2], red2[2];
    int b = blockIdx.x, j = threadIdx.x;
    int s = segs[b], n = segn[b];
    float zr = 0.f, zi = 0.f;
    int p = 0;
    // unroll-2: two h-rows in flight; accumulation ORDER unchanged (fp32-exact)
    for (; p + 1 < n; p += 2) {
        int e0 = order[s + p], e1 = order[s + p + 1];
        float hv0 = h[(size_t)e0 * HIDX + j];
        float hv1 = h[(size_t)e1 * HIDX + j];
        float cv0 = ct[p * HIDX + j],      sv0 = st[p * HIDX + j];
        float cv1 = ct[(p + 1) * HIDX + j], sv1 = st[(p + 1) * HIDX + j];
        zr += hv0 * cv0; zi += hv0 * sv0;
        zr += hv1 * cv1; zi += hv1 * sv1;
    }
    if (p < n) {
        int e = order[s + p];
        float hv = h[(size_t)e * HIDX + j];
        zr += hv * ct[p * HIDX + j];
        zi += hv * st[p * HIDX + j];
    }
    float nf = (float)n;
    float zrev = zr + nf * cw[j] + cb[j];
    zrow[j] = zrev;
    zim[(size_t)b * HIDX + j] = zi;
    __syncthreads();

    // size MLP (threads 0..127 active; all threads hit barriers)
    float v = 0.0f;
    if (j < SMID) {
        v = sb1[j];
        for (int k = 0; k < HIDX; k++) v += zrow[k] * sw1[k * SMID + j];
    }
    float sa = v;
#pragma unroll
    for (int off = 32; off; off >>= 1) sa += __shfl_xor(sa, off, 64);
    if (j < SMID && (j & 63) == 0) red0[j >> 6] = sa;
    __syncthreads();
    float mean = (red0[0] + red0[1]) / 128.0f;
    float d = v - mean;
    float q = d * d;
#pragma unroll
    for (int off = 32; off; off >>= 1) q += __shfl_xor(q, off, 64);
    if (j < SMID && (j & 63) == 0) red1[j >> 6] = q;
    __syncthreads();
    float var = (red1[0] + red1[1]) / 128.0f;
    float p2 = 0.0f;
    if (j < SMID) {
        float lv = d * (1.0f / sqrtf(var + 1e-5f)) * sg[j] + sbe[j];
        p2 = mishf(lv) * sw2[j];
    }
#pragma unroll
    for (int off = 32; off; off >>= 1) p2 += __shfl_xor(p2, off, 64);
    if (j < SMID && (j & 63) == 0) red2[j >> 6] = p2;
    __syncthreads();
    float h2 = red2[0] + red2[1] + sb2[0];
    float npf = fmaxf(rintf(h2), 0.0f);     // rintf == round-half-even == jnp.round
    int npi = min((int)npf, NMAXX);
    zcre[(size_t)b * HIDX + j] = zrow[j] - (npf * cw[j] + cb[j]);
    if (j < NMAXX) out_mask[b * NMAXX + j] = (j < npi) ? 1.0f : 0.0f;
    if (j == 0) {
        out_np[b] = (float)npi;
        int base = atomicAdd(wcount, npi);
        for (int m = 0; m < npi; m++) wlist[base + m] = (b << 5) | m;
    }
}

// decoder over compacted worklist
__global__ __launch_bounds__(256) void k_dec(const float* __restrict__ zcre,
    const float* __restrict__ zim, const int* __restrict__ wcount,
    const int* __restrict__ wlist, const float* __restrict__ ct,
    const float* __restrict__ st, const float* __restrict__ w1,
    const float* __restrict__ b1, const float* __restrict__ w2,
    const float* __restrict__ b2, float* __restrict__ xr) {
    __shared__ float zp[HIDX];
    __shared__ float a[DMID];
    int tid = threadIdx.x;
    int count = *wcount;
    for (int it = blockIdx.x; it < count; it += gridDim.x) {
        int wv = wlist[it];
        int b = wv >> 5, m = wv & 31;
        float cv = ct[m * HIDX + tid], sv = st[m * HIDX + tid];
        zp[tid] = zcre[(size_t)b * HIDX + tid] * cv - zim[(size_t)b * HIDX + tid] * sv;
        __syncthreads();
        if (tid < DMID) {
            float v = b1[tid];
            for (int k = 0; k < HIDX; k++) v += zp[k] * w1[k * DMID + tid];
            a[tid] = mishf(v);
        }
        __syncthreads();
        if (tid < DIMX) {
            float v = b2[tid];
            for (int k = 0; k < DMID; k++) v += a[k] * w2[k * DIMX + tid];
            xr[((size_t)b * NMAXX + m) * DIMX + tid] = v;
        }
        __syncthreads();
    }
}

extern "C" void kernel_launch(void* const* d_in, const int* in_sizes, int n_in,
                              void* d_out, int out_size, void* d_ws, size_t ws_size,
                              hipStream_t stream) {
    const float* x      = (const float*)d_in[0];
    const int*   batch  = (const int*)d_in[1];
    const float* rank_w = (const float*)d_in[2];
    const float* rank_b = (const float*)d_in[3];
    const float* vw1    = (const float*)d_in[4];
    const float* vb1    = (const float*)d_in[5];
    const float* vlg    = (const float*)d_in[6];
    const float* vlb    = (const float*)d_in[7];
    const float* vw2    = (const float*)d_in[8];
    const float* vb2    = (const float*)d_in[9];
    const float* cw     = (const float*)d_in[10];
    const float* cb     = (const float*)d_in[11];
    const float* sw1    = (const float*)d_in[12];
    const float* sb1    = (const float*)d_in[13];
    const float* slg    = (const float*)d_in[14];
    const float* slb    = (const float*)d_in[15];
    const float* sw2    = (const float*)d_in[16];
    const float* sb2    = (const float*)d_in[17];
    const float* dw1    = (const float*)d_in[18];
    const float* db1    = (const float*)d_in[19];
    const float* dw2    = (const float*)d_in[20];
    const float* db2    = (const float*)d_in[21];

    char* ws = (char*)d_ws;
    size_t off = 0;
    auto alloc = [&](size_t bytes) {
        void* p = ws + off;
        off += (bytes + 255) & ~(size_t)255;
        return p;
    };
    float* mag    = (float*)alloc((size_t)NTOTX * 4);
    int*   segs   = (int*)alloc((size_t)NBX * 4);
    int*   segn   = (int*)alloc((size_t)NBX * 4);
    int*   order  = (int*)alloc((size_t)NTOTX * 4);
    float* ct     = (float*)alloc((size_t)KTAB * HIDX * 4);
    float* st     = (float*)alloc((size_t)KTAB * HIDX * 4);
    float* zim    = (float*)alloc((size_t)NBX * HIDX * 4);
    float* zcre   = (float*)alloc((size_t)NBX * HIDX * 4);
    int*   wcount = (int*)alloc(256);
    int*   wlist  = (int*)alloc((size_t)NBX * NMAXX * 4);
    float* h      = (float*)alloc((size_t)NTOTX * HIDX * 4);

    float* out_xr   = (float*)d_out;
    float* out_mask = out_xr + (size_t)NBX * NMAXX * DIMX;
    float* out_np   = out_mask + (size_t)NBX * NMAXX;

    hipLaunchKernelGGL(k_prep, dim3(8449 + 2048), dim3(256), 0, stream,
                       x, rank_w, rank_b, batch, mag, segs, segn, ct, st,
                       wcount, (float4*)out_xr);
    hipLaunchKernelGGL(k_rank, dim3(NTOTX / 256), dim3(256), 0, stream,
                       batch, mag, segs, segn, order);
    hipLaunchKernelGGL(k_enc,  dim3(NTOTX / EROWS), dim3(256), 0, stream,
                       x, vw1, vb1, vlg, vlb, vw2, vb2, h);
    hipLaunchKernelGGL(k_z,    dim3(NBX), dim3(HIDX), 0, stream,
                       h, order, segs, segn, ct, st, cw, cb,
                       sw1, sb1, slg, slb, sw2, sb2,
                       zcre, zim, out_mask, out_np, wcount, wlist);
    hipLaunchKernelGGL(k_dec,  dim3(2048), dim3(256), 0, stream,
                       zcre, zim, wcount, wlist, ct, st, dw1, db1, dw2, db2, out_xr);
    (void)in_sizes; (void)n_in; (void)out_size; (void)ws_size;
}